// Round 13
// baseline (197.504 us; speedup 1.0000x reference)
//
#include <hip/hip_runtime.h>
#include <hip/hip_bf16.h>

#define NNODES 30000
#define NEDGES 480000
#define TE (NEDGES + NNODES)   // edges incl. self-loops
#define FH 256                 // hidden width (H*C)
#define NH 8                   // heads
#define CSRB 120               // csr grid blocks (<=256 CUs -> co-resident)
#define CHUNK 250              // nodes per csr block (120*250 = 30000)

typedef unsigned short ushort_t;
typedef __attribute__((ext_vector_type(8))) _Float16 f16x8;
typedef __attribute__((ext_vector_type(2))) _Float16 f16x2;
typedef __attribute__((ext_vector_type(4))) float f32x4;

// ---------------- fp16 helpers ----------------
__device__ __forceinline__ unsigned f2h2(float a, float b) {  // pack 2 floats
    f16x2 h;
    h.x = (_Float16)a;
    h.y = (_Float16)b;
    return __builtin_bit_cast(unsigned, h);
}

// ---------------- prep: zero counts + barrier state + weight transpose ----------
__global__ __launch_bounds__(256) void prep_kernel(
    int* __restrict__ counts, int* __restrict__ bar,
    const float* __restrict__ W1, const float* __restrict__ W2,
    _Float16* __restrict__ t1, _Float16* __restrict__ t2) {
    int i = blockIdx.x * 256 + threadIdx.x;
    if (i < NNODES) counts[i] = 0;
    if (i < 8) bar[i] = 0;
    if (i < 128 * 256) {
        int n = i & 255, k = i >> 8;            // k in [0,128)
        t1[n * 128 + k] = (_Float16)W1[i];
    }
    int j = i - 128 * 256;
    if (j >= 0 && j < 256 * 256) {
        int n = j & 255, k = j >> 8;            // k in [0,256)
        t2[n * 256 + k] = (_Float16)W2[j];
    }
}

// ---------------- single-kernel CSR build with manual grid barriers ----------
// 120 blocks x 256 threads: co-resident by construction (256 CUs, 1KB LDS,
// low VGPR). Device-scope atomics + threadfence give cross-XCD visibility.
__device__ __forceinline__ void gridbar(int* __restrict__ bar, int phase, int tid) {
    __syncthreads();
    if (tid == 0) {
        __threadfence();                         // release all prior writes
        atomicAdd(&bar[phase], 1);               // device-scope
        while (__hip_atomic_load(&bar[phase], __ATOMIC_ACQUIRE,
                                 __HIP_MEMORY_SCOPE_AGENT) < CSRB) { }
    }
    __syncthreads();
}

__global__ __launch_bounds__(256) void csr_kernel(
    const int* __restrict__ ei, int* __restrict__ counts,
    int* __restrict__ rp, int* __restrict__ cursor, int* __restrict__ ssrc,
    int* __restrict__ bar, int* __restrict__ bsum) {

    __shared__ int s[256];
    const int tid  = threadIdx.x;
    const int bid  = blockIdx.x;
    const int gtid = bid * 256 + tid;
    const int gsz  = CSRB * 256;

    // ---- phase 1: degree histogram (device atomics) ----
    for (int e = gtid; e < TE; e += gsz) {
        int d = (e < NEDGES) ? ei[NEDGES + e] : (e - NEDGES);
        atomicAdd(&counts[d], 1);
    }
    gridbar(bar, 0, tid);

    // ---- phase 2: local exclusive scan of this block's 250-node chunk ----
    const int base = bid * CHUNK;
    int v = (tid < CHUNK) ? counts[base + tid] : 0;
    s[tid] = v;
    __syncthreads();
    for (int off = 1; off < 256; off <<= 1) {
        int t = (tid >= off) ? s[tid - off] : 0;
        __syncthreads();
        s[tid] += t;
        __syncthreads();
    }
    if (tid < CHUNK) rp[base + tid] = s[tid] - v;    // local exclusive prefix
    if (tid == 255) bsum[bid] = s[255];
    gridbar(bar, 1, tid);

    // ---- phase 3: block 0 scans the 120 block sums (exclusive) ----
    if (bid == 0) {
        int vv = (tid < CSRB) ? bsum[tid] : 0;
        s[tid] = vv;
        __syncthreads();
        for (int off = 1; off < 256; off <<= 1) {
            int t = (tid >= off) ? s[tid - off] : 0;
            __syncthreads();
            s[tid] += t;
            __syncthreads();
        }
        if (tid < CSRB) bsum[tid] = s[tid] - vv;
    }
    gridbar(bar, 2, tid);

    // ---- phase 4: add block offsets, fan out rp/cursor ----
    if (tid < CHUNK) {
        int r = rp[base + tid] + bsum[bid];
        rp[base + tid] = r;
        cursor[base + tid] = r;
    }
    if (gtid == 0) rp[NNODES] = TE;    // total is compile-time constant
    gridbar(bar, 3, tid);

    // ---- phase 5: scatter-fill src lists ----
    for (int e = gtid; e < TE; e += gsz) {
        int sv, d;
        if (e < NEDGES) { sv = ei[e]; d = ei[NEDGES + e]; }
        else            { sv = e - NEDGES; d = sv; }
        int pos = atomicAdd(&cursor[d], 1);
        ssrc[pos] = sv;
    }
}

// ---------------- fp16 MFMA GEMM (h = X @ W) + fused alpha dots ----------------
// BM=128 x BN=256 (full width: A read ONCE), BK=32, 512 threads = 8 waves of
// 64x64 (4x4 frags 16x16x32). CVT=true: A is fp32, converted during staging.
template<int K, bool CVT>
__global__ __launch_bounds__(512) void gemm_mfma(
    const void* __restrict__ Araw,  const _Float16* __restrict__ Bt,   // [M][K], [256][K]
    const float* __restrict__ ASRC, const float* __restrict__ ADST,
    _Float16* __restrict__ HFh, float* __restrict__ AS, float* __restrict__ AD) {

    constexpr int LDK = 40;   // pad: 80B row stride, 16B aligned chunks
    __shared__ _Float16 Ah[128][LDK];   // 10 KB
    __shared__ _Float16 Bh[256][LDK];   // 20 KB

    const int tid  = threadIdx.x;
    const int lane = tid & 63;
    const int wid  = tid >> 6;          // 0..7
    const int m0 = blockIdx.x * 128;
    const int wm = (wid & 1) * 64;      // 0,64
    const int wn = (wid >> 1) * 64;     // 0,64,128,192
    const int q = lane >> 4;            // quarter-wave
    const int c = lane & 15;

    f32x4 acc[4][4];
#pragma unroll
    for (int mi = 0; mi < 4; ++mi)
#pragma unroll
        for (int ni = 0; ni < 4; ++ni) acc[mi][ni] = (f32x4){0.f, 0.f, 0.f, 0.f};

    for (int k0 = 0; k0 < K; k0 += 32) {
        __syncthreads();
        {   // ---- stage A: 128 rows x 32 halves = 512 units, 1 rep ----
            int row = tid >> 2;                 // 0..127
            int ch  = (tid & 3) * 8;            // k-chunk of 8 halves
            int gr = m0 + row;
            uint4 v = make_uint4(0u, 0u, 0u, 0u);
            if (gr < NNODES) {
                if (CVT) {
                    const float* Xf = (const float*)Araw;
                    float4 f0 = *reinterpret_cast<const float4*>(&Xf[(size_t)gr * K + k0 + ch]);
                    float4 f1 = *reinterpret_cast<const float4*>(&Xf[(size_t)gr * K + k0 + ch + 4]);
                    v.x = f2h2(f0.x, f0.y); v.y = f2h2(f0.z, f0.w);
                    v.z = f2h2(f1.x, f1.y); v.w = f2h2(f1.z, f1.w);
                } else {
                    const _Float16* Ah_g = (const _Float16*)Araw;
                    v = *reinterpret_cast<const uint4*>(&Ah_g[(size_t)gr * K + k0 + ch]);
                }
            }
            *reinterpret_cast<uint4*>(&Ah[row][ch]) = v;
        }
#pragma unroll
        for (int rep = 0; rep < 2; ++rep) {   // ---- stage B: 256 rows = 1024 units ----
            int idx = tid + 512 * rep;          // 0..1023
            int row = idx >> 2;                 // 0..255
            int ch  = (idx & 3) * 8;
            uint4 bv = *reinterpret_cast<const uint4*>(&Bt[(size_t)row * K + k0 + ch]);
            *reinterpret_cast<uint4*>(&Bh[row][ch]) = bv;
        }
        __syncthreads();

        const int koff = q * 8;
        f16x8 fa[4], fb[4];
#pragma unroll
        for (int mi = 0; mi < 4; ++mi)
            fa[mi] = *reinterpret_cast<const f16x8*>(&Ah[wm + mi * 16 + c][koff]);
#pragma unroll
        for (int ni = 0; ni < 4; ++ni)
            fb[ni] = *reinterpret_cast<const f16x8*>(&Bh[wn + ni * 16 + c][koff]);
#pragma unroll
        for (int mi = 0; mi < 4; ++mi)
#pragma unroll
            for (int ni = 0; ni < 4; ++ni)
                acc[mi][ni] = __builtin_amdgcn_mfma_f32_16x16x32_f16(fa[mi], fb[ni], acc[mi][ni], 0, 0, 0);
    }

    // ---- epilogue: h (fp16) stores + fused per-head alpha dots (fp32 acc) ----
    float as_v[4], ad_v[4];
#pragma unroll
    for (int ni = 0; ni < 4; ++ni) {
        as_v[ni] = ASRC[wn + ni * 16 + c];
        ad_v[ni] = ADST[wn + ni * 16 + c];
    }
    const int head0 = wn >> 5;   // this wave covers heads head0, head0+1

#pragma unroll
    for (int mi = 0; mi < 4; ++mi) {
#pragma unroll
        for (int j = 0; j < 4; ++j) {
            int row = m0 + wm + mi * 16 + q * 4 + j;
            bool ok = row < NNODES;
            if (ok) {
#pragma unroll
                for (int ni = 0; ni < 4; ++ni)
                    HFh[(size_t)row * FH + wn + ni * 16 + c] = (_Float16)acc[mi][ni][j];
            }
            float ps0 = acc[mi][0][j] * as_v[0] + acc[mi][1][j] * as_v[1];
            float ps1 = acc[mi][2][j] * as_v[2] + acc[mi][3][j] * as_v[3];
            float pd0 = acc[mi][0][j] * ad_v[0] + acc[mi][1][j] * ad_v[1];
            float pd1 = acc[mi][2][j] * ad_v[2] + acc[mi][3][j] * ad_v[3];
#pragma unroll
            for (int off = 8; off >= 1; off >>= 1) {
                ps0 += __shfl_xor(ps0, off);
                ps1 += __shfl_xor(ps1, off);
                pd0 += __shfl_xor(pd0, off);
                pd1 += __shfl_xor(pd1, off);
            }
            if (ok && c == 0) {
                AS[row * NH + head0]     = ps0;
                AS[row * NH + head0 + 1] = ps1;
                AD[row * NH + head0]     = pd0;
                AD[row * NH + head0 + 1] = pd1;
            }
        }
    }
}

// ---------------- Fused softmax + gather aggregation: one WAVE per node -------
// (unchanged -- measured at ~93% of the 6.3 TB/s effective-BW gather roofline)
template<bool FINAL>
__global__ __launch_bounds__(256) void aggregate(
    const _Float16* __restrict__ HFh,
    const float* __restrict__ AS, const float* __restrict__ AD,
    const int* __restrict__ rp, const int* __restrict__ ssrc,
    const float* __restrict__ BIAS,
    _Float16* __restrict__ X2H,
    const float* __restrict__ WL, const float* __restrict__ BL,
    float* __restrict__ OUT) {

    __shared__ float wslab[4][64 * 10];   // 10.2 KB; per-wave private slab

    const int tid  = threadIdx.x;
    const int lane = tid & 63;
    const int wid  = tid >> 6;
    const int node = __builtin_amdgcn_readfirstlane(blockIdx.x * 4 + wid);
    const int epar = lane >> 5;        // which edge of the pair (phase B)
    const int cg   = lane & 31;        // channel group: owns channels cg*8..cg*8+7
    const int hh   = cg >> 2;          // head of these channels
    const int c8   = cg * 8;
    float* wl = wslab[wid];

    const int p0  = rp[node];
    const int deg = rp[node + 1] - p0;   // >= 1 (self-loop)

    const float4 ad0 = *reinterpret_cast<const float4*>(&AD[node * NH]);
    const float4 ad1 = *reinterpret_cast<const float4*>(&AD[node * NH + 4]);

    float a0=0.f,a1=0.f,a2=0.f,a3=0.f,a4=0.f,a5=0.f,a6=0.f,a7=0.f;
    float den = 0.f;

    for (int base = 0; base < deg; base += 64) {
        const int ne = min(64, deg - base);

        // ---- phase A: lane e computes w[8] + src for edge base+e ----
        if (lane < ne) {
            int s = ssrc[p0 + base + lane];
            float4 as0 = *reinterpret_cast<const float4*>(&AS[s * NH]);
            float4 as1 = *reinterpret_cast<const float4*>(&AS[s * NH + 4]);
            float sv[8] = {as0.x + ad0.x, as0.y + ad0.y, as0.z + ad0.z, as0.w + ad0.w,
                           as1.x + ad1.x, as1.y + ad1.y, as1.z + ad1.z, as1.w + ad1.w};
            float* wp = &wl[lane * 10];
#pragma unroll
            for (int h = 0; h < 8; ++h) {
                float t = sv[h] > 0.f ? sv[h] : 0.2f * sv[h];
                wp[h] = __expf(t);
            }
            wp[8] = __int_as_float(s);
        }
        // wave-local LDS producer->consumer ordering (same wave, no barrier)
        asm volatile("s_waitcnt lgkmcnt(0)" ::: "memory");

        // ---- phase B: half-waves gather h rows; w + src from LDS ----
#pragma unroll 4
        for (int e0 = 0; e0 < ne; e0 += 2) {
            const int  e   = e0 + epar;
            const bool act = e < ne;
            const int  ee  = act ? e : 0;
            const int  sa  = __float_as_int(wl[ee * 10 + 8]);
            const float wr = wl[ee * 10 + hh];
            const float w  = act ? wr : 0.f;
            den += w;
            const f16x8 hv = *reinterpret_cast<const f16x8*>(&HFh[(size_t)sa * FH + c8]);
            a0 = fmaf((float)hv[0], w, a0);
            a1 = fmaf((float)hv[1], w, a1);
            a2 = fmaf((float)hv[2], w, a2);
            a3 = fmaf((float)hv[3], w, a3);
            a4 = fmaf((float)hv[4], w, a4);
            a5 = fmaf((float)hv[5], w, a5);
            a6 = fmaf((float)hv[6], w, a6);
            a7 = fmaf((float)hv[7], w, a7);
        }
    }

    // combine the two edge-parallel halves
    a0 += __shfl_xor(a0, 32); a1 += __shfl_xor(a1, 32);
    a2 += __shfl_xor(a2, 32); a3 += __shfl_xor(a3, 32);
    a4 += __shfl_xor(a4, 32); a5 += __shfl_xor(a5, 32);
    a6 += __shfl_xor(a6, 32); a7 += __shfl_xor(a7, 32);
    den += __shfl_xor(den, 32);

    const float inv = 1.f / (den + 1e-16f);
    const float4 b0 = *reinterpret_cast<const float4*>(&BIAS[c8]);
    const float4 b1 = *reinterpret_cast<const float4*>(&BIAS[c8 + 4]);
    float o[8];
    o[0] = fmaf(a0, inv, b0.x); o[1] = fmaf(a1, inv, b0.y);
    o[2] = fmaf(a2, inv, b0.z); o[3] = fmaf(a3, inv, b0.w);
    o[4] = fmaf(a4, inv, b1.x); o[5] = fmaf(a5, inv, b1.y);
    o[6] = fmaf(a6, inv, b1.z); o[7] = fmaf(a7, inv, b1.w);
#pragma unroll
    for (int j = 0; j < 8; ++j) o[j] = o[j] > 0.f ? o[j] : expm1f(o[j]);

    if (!FINAL) {
        // emit fp16 for the next GEMM (4 channels per half-wave)
        uint2 st;
        st.x = f2h2(o[epar * 4 + 0], o[epar * 4 + 1]);
        st.y = f2h2(o[epar * 4 + 2], o[epar * 4 + 3]);
        *reinterpret_cast<uint2*>(&X2H[(size_t)node * FH + c8 + epar * 4]) = st;
    } else {
        const float4 w0 = *reinterpret_cast<const float4*>(&WL[c8]);
        const float4 w1 = *reinterpret_cast<const float4*>(&WL[c8 + 4]);
        float pl = fmaf(o[0], w0.x, fmaf(o[1], w0.y, fmaf(o[2], w0.z, o[3] * w0.w)));
        pl = fmaf(o[4], w1.x, fmaf(o[5], w1.y, fmaf(o[6], w1.z, fmaf(o[7], w1.w, pl))));
#pragma unroll
        for (int off = 16; off >= 1; off >>= 1) pl += __shfl_xor(pl, off);
        if (lane == 0) OUT[node] = pl + BL[0];
    }
}

// ---------------- launch ----------------
extern "C" void kernel_launch(void* const* d_in, const int* in_sizes, int n_in,
                              void* d_out, int out_size, void* d_ws, size_t ws_size,
                              hipStream_t stream) {
    const float* x   = (const float*)d_in[0];
    const int*   ei  = (const int*)d_in[1];
    const float* W1  = (const float*)d_in[2];
    const float* a1s = (const float*)d_in[3];
    const float* a1d = (const float*)d_in[4];
    const float* b1  = (const float*)d_in[5];
    const float* W2  = (const float*)d_in[6];
    const float* a2s = (const float*)d_in[7];
    const float* a2d = (const float*)d_in[8];
    const float* b2  = (const float*)d_in[9];
    const float* Wl  = (const float*)d_in[10];
    const float* bl  = (const float*)d_in[11];
    float* out = (float*)d_out;

    char* w = (char*)d_ws;
    auto alloc = [&](size_t bytes) -> char* {
        char* p = w;
        w += (bytes + 255) & ~size_t(255);
        return p;
    };
    int*   counts = (int*)alloc((size_t)NNODES * 4);
    int*   rp     = (int*)alloc((size_t)(NNODES + 1) * 4);
    int*   cursor = (int*)alloc((size_t)NNODES * 4);
    int*   bar    = (int*)alloc(8 * 4);
    int*   bsum   = (int*)alloc((size_t)CSRB * 4);
    int*   ssrc   = (int*)alloc((size_t)TE * 4);
    _Float16* hfh = (_Float16*)alloc((size_t)NNODES * FH * 2);
    _Float16* x2h = (_Float16*)alloc((size_t)NNODES * FH * 2);    // fp16 layer-2 A
    float* asb    = (float*)alloc((size_t)NNODES * NH * 4);
    float* adb    = (float*)alloc((size_t)NNODES * NH * 4);
    _Float16* w1t = (_Float16*)alloc((size_t)128 * 256 * 2);
    _Float16* w2t = (_Float16*)alloc((size_t)256 * 256 * 2);

    prep_kernel<<<384, 256, 0, stream>>>(counts, bar, W1, W2, w1t, w2t);
    csr_kernel<<<CSRB, 256, 0, stream>>>(ei, counts, rp, cursor, ssrc, bar, bsum);

    const int gblocks = (NNODES + 127) / 128;
    gemm_mfma<128, true><<<gblocks, 512, 0, stream>>>(x, w1t, a1s, a1d, hfh, asb, adb);
    aggregate<false><<<NNODES / 4, 256, 0, stream>>>(hfh, asb, adb, rp, ssrc, b1,
                                                     x2h, nullptr, nullptr, nullptr);
    gemm_mfma<256, false><<<gblocks, 512, 0, stream>>>(x2h, w2t, a2s, a2d, hfh, asb, adb);
    aggregate<true><<<NNODES / 4, 256, 0, stream>>>(hfh, asb, adb, rp, ssrc, b2,
                                                    nullptr, Wl, bl, out);
}

// Round 14
// 172.049 us; speedup vs baseline: 1.1479x; 1.1479x over previous
//
#include <hip/hip_runtime.h>
#include <hip/hip_bf16.h>

#define NNODES 30000
#define NEDGES 480000
#define TE (NEDGES + NNODES)   // edges incl. self-loops
#define FH 256                 // hidden width (H*C)
#define NH 8                   // heads
#define NSB ((NNODES + 255) / 256)   // scan blocks = 118
#define CNTB 235               // count-role blocks appended to gemm1

typedef unsigned short ushort_t;
typedef __attribute__((ext_vector_type(8))) _Float16 f16x8;
typedef __attribute__((ext_vector_type(2))) _Float16 f16x2;
typedef __attribute__((ext_vector_type(4))) float f32x4;

// ---------------- fp16 helpers ----------------
__device__ __forceinline__ unsigned f2h2(float a, float b) {  // pack 2 floats
    f16x2 h;
    h.x = (_Float16)a;
    h.y = (_Float16)b;
    return __builtin_bit_cast(unsigned, h);
}

// ---------------- prep: zero counts + scan-pub slots + weight transpose -------
__global__ __launch_bounds__(256) void prep_kernel(
    int* __restrict__ counts, unsigned long long* __restrict__ pub,
    const float* __restrict__ W1, const float* __restrict__ W2,
    _Float16* __restrict__ t1, _Float16* __restrict__ t2) {
    int i = blockIdx.x * 256 + threadIdx.x;
    if (i < NNODES) counts[i] = 0;
    if (i < NSB) pub[i] = 0ULL;
    if (i < 128 * 256) {
        int n = i & 255, k = i >> 8;            // k in [0,128)
        t1[n * 128 + k] = (_Float16)W1[i];
    }
    int j = i - 128 * 256;
    if (j >= 0 && j < 256 * 256) {
        int n = j & 255, k = j >> 8;            // k in [0,256)
        t2[n * 256 + k] = (_Float16)W2[j];
    }
}

// ---------------- decoupled-lookback scan (single dispatch) -------------------
// 118 blocks x 256. Each block: local inclusive scan of its 256 counts,
// PUBLISH aggregate (release, flag bit 63) BEFORE polling -> deadlock-free.
// Lanes 0..bid-1 poll DISTINCT predecessor slots in parallel (no single-line
// contention), tree-reduce, add offset, fan out rp/cursor.
__global__ __launch_bounds__(256) void scan_lb(
    const int* __restrict__ counts, int* __restrict__ rp,
    int* __restrict__ cursor, unsigned long long* __restrict__ pub) {

    __shared__ int s[256];
    __shared__ int ppart[128];
    const int tid = threadIdx.x;
    const int bid = blockIdx.x;
    const int i = bid * 256 + tid;

    int v = (i < NNODES) ? counts[i] : 0;
    s[tid] = v;
    __syncthreads();
    for (int off = 1; off < 256; off <<= 1) {
        int t = (tid >= off) ? s[tid - off] : 0;
        __syncthreads();
        s[tid] += t;
        __syncthreads();
    }
    // publish own aggregate first (non-blocking; guarantees global progress)
    if (tid == 255)
        __hip_atomic_store(&pub[bid], (1ULL << 63) | (unsigned)s[255],
                           __ATOMIC_RELEASE, __HIP_MEMORY_SCOPE_AGENT);

    // poll predecessors: lane t handles pred t (bid <= 117 < 128)
    if (tid < 128) {
        int total = 0;
        if (tid < bid) {
            unsigned long long val;
            do {
                val = __hip_atomic_load(&pub[tid], __ATOMIC_ACQUIRE,
                                        __HIP_MEMORY_SCOPE_AGENT);
            } while (!(val >> 63));
            total = (int)(unsigned)val;
        }
        ppart[tid] = total;
    }
    __syncthreads();
    for (int off = 64; off >= 1; off >>= 1) {
        if (tid < off) ppart[tid] += ppart[tid + off];
        __syncthreads();
    }
    const int boff = ppart[0];

    if (i < NNODES) {
        int r = boff + s[tid] - v;   // exclusive prefix
        rp[i] = r;
        cursor[i] = r;
    }
    if (i == 0) rp[NNODES] = TE;     // total is a compile-time constant
}

__global__ __launch_bounds__(512) void fill_kernel(const int* __restrict__ ei,
                                                   int* __restrict__ cursor,
                                                   int* __restrict__ ssrc) {
    int e = blockIdx.x * 512 + threadIdx.x;
    if (e >= TE) return;
    int s, d;
    if (e < NEDGES) { s = ei[e]; d = ei[NEDGES + e]; }
    else            { s = e - NEDGES; d = s; }
    int pos = atomicAdd(&cursor[d], 1);
    ssrc[pos] = s;
}

// ---------------- fp16 MFMA GEMM (h = X @ W) + fused alpha dots ----------------
// BM=128 x BN=256 (A read ONCE), BK=32, 512 threads = 8 waves of 64x64.
// CVT=true: A is fp32, converted during staging. Blocks with blockIdx >= gb
// take the COUNT role instead (degree histogram) -- independent work fused
// into the same dispatch to hide it under the GEMM (gemm2 passes gb=grid).
template<int K, bool CVT>
__global__ __launch_bounds__(512) void gemm_mfma(
    const void* __restrict__ Araw,  const _Float16* __restrict__ Bt,   // [M][K], [256][K]
    const float* __restrict__ ASRC, const float* __restrict__ ADST,
    _Float16* __restrict__ HFh, float* __restrict__ AS, float* __restrict__ AD,
    int gb, const int* __restrict__ ei, int* __restrict__ counts) {

    constexpr int LDK = 40;   // pad: 80B row stride, 16B aligned chunks
    __shared__ _Float16 Ah[128][LDK];   // 10 KB
    __shared__ _Float16 Bh[256][LDK];   // 20 KB

    const int tid  = threadIdx.x;

    if ((int)blockIdx.x >= gb) {         // ---- count role ----
        const int cb = blockIdx.x - gb;
        for (int e = cb * 512 + tid; e < TE; e += CNTB * 512) {
            int d = (e < NEDGES) ? ei[NEDGES + e] : (e - NEDGES);
            atomicAdd(&counts[d], 1);
        }
        return;
    }

    const int lane = tid & 63;
    const int wid  = tid >> 6;          // 0..7
    const int m0 = blockIdx.x * 128;
    const int wm = (wid & 1) * 64;      // 0,64
    const int wn = (wid >> 1) * 64;     // 0,64,128,192
    const int q = lane >> 4;            // quarter-wave
    const int c = lane & 15;

    f32x4 acc[4][4];
#pragma unroll
    for (int mi = 0; mi < 4; ++mi)
#pragma unroll
        for (int ni = 0; ni < 4; ++ni) acc[mi][ni] = (f32x4){0.f, 0.f, 0.f, 0.f};

    for (int k0 = 0; k0 < K; k0 += 32) {
        __syncthreads();
        {   // ---- stage A: 128 rows x 32 halves = 512 units, 1 rep ----
            int row = tid >> 2;                 // 0..127
            int ch  = (tid & 3) * 8;            // k-chunk of 8 halves
            int gr = m0 + row;
            uint4 v = make_uint4(0u, 0u, 0u, 0u);
            if (gr < NNODES) {
                if (CVT) {
                    const float* Xf = (const float*)Araw;
                    float4 f0 = *reinterpret_cast<const float4*>(&Xf[(size_t)gr * K + k0 + ch]);
                    float4 f1 = *reinterpret_cast<const float4*>(&Xf[(size_t)gr * K + k0 + ch + 4]);
                    v.x = f2h2(f0.x, f0.y); v.y = f2h2(f0.z, f0.w);
                    v.z = f2h2(f1.x, f1.y); v.w = f2h2(f1.z, f1.w);
                } else {
                    const _Float16* Ah_g = (const _Float16*)Araw;
                    v = *reinterpret_cast<const uint4*>(&Ah_g[(size_t)gr * K + k0 + ch]);
                }
            }
            *reinterpret_cast<uint4*>(&Ah[row][ch]) = v;
        }
#pragma unroll
        for (int rep = 0; rep < 2; ++rep) {   // ---- stage B: 256 rows = 1024 units ----
            int idx = tid + 512 * rep;          // 0..1023
            int row = idx >> 2;                 // 0..255
            int ch  = (idx & 3) * 8;
            uint4 bv = *reinterpret_cast<const uint4*>(&Bt[(size_t)row * K + k0 + ch]);
            *reinterpret_cast<uint4*>(&Bh[row][ch]) = bv;
        }
        __syncthreads();

        const int koff = q * 8;
        f16x8 fa[4], fb[4];
#pragma unroll
        for (int mi = 0; mi < 4; ++mi)
            fa[mi] = *reinterpret_cast<const f16x8*>(&Ah[wm + mi * 16 + c][koff]);
#pragma unroll
        for (int ni = 0; ni < 4; ++ni)
            fb[ni] = *reinterpret_cast<const f16x8*>(&Bh[wn + ni * 16 + c][koff]);
#pragma unroll
        for (int mi = 0; mi < 4; ++mi)
#pragma unroll
            for (int ni = 0; ni < 4; ++ni)
                acc[mi][ni] = __builtin_amdgcn_mfma_f32_16x16x32_f16(fa[mi], fb[ni], acc[mi][ni], 0, 0, 0);
    }

    // ---- epilogue: h (fp16) stores + fused per-head alpha dots (fp32 acc) ----
    float as_v[4], ad_v[4];
#pragma unroll
    for (int ni = 0; ni < 4; ++ni) {
        as_v[ni] = ASRC[wn + ni * 16 + c];
        ad_v[ni] = ADST[wn + ni * 16 + c];
    }
    const int head0 = wn >> 5;   // this wave covers heads head0, head0+1

#pragma unroll
    for (int mi = 0; mi < 4; ++mi) {
#pragma unroll
        for (int j = 0; j < 4; ++j) {
            int row = m0 + wm + mi * 16 + q * 4 + j;
            bool ok = row < NNODES;
            if (ok) {
#pragma unroll
                for (int ni = 0; ni < 4; ++ni)
                    HFh[(size_t)row * FH + wn + ni * 16 + c] = (_Float16)acc[mi][ni][j];
            }
            float ps0 = acc[mi][0][j] * as_v[0] + acc[mi][1][j] * as_v[1];
            float ps1 = acc[mi][2][j] * as_v[2] + acc[mi][3][j] * as_v[3];
            float pd0 = acc[mi][0][j] * ad_v[0] + acc[mi][1][j] * ad_v[1];
            float pd1 = acc[mi][2][j] * ad_v[2] + acc[mi][3][j] * ad_v[3];
#pragma unroll
            for (int off = 8; off >= 1; off >>= 1) {
                ps0 += __shfl_xor(ps0, off);
                ps1 += __shfl_xor(ps1, off);
                pd0 += __shfl_xor(pd0, off);
                pd1 += __shfl_xor(pd1, off);
            }
            if (ok && c == 0) {
                AS[row * NH + head0]     = ps0;
                AS[row * NH + head0 + 1] = ps1;
                AD[row * NH + head0]     = pd0;
                AD[row * NH + head0 + 1] = pd1;
            }
        }
    }
}

// ---------------- Fused softmax + gather aggregation: one WAVE per node -------
// (unchanged -- measured at ~93% of the 6.3 TB/s effective-BW gather roofline)
template<bool FINAL>
__global__ __launch_bounds__(256) void aggregate(
    const _Float16* __restrict__ HFh,
    const float* __restrict__ AS, const float* __restrict__ AD,
    const int* __restrict__ rp, const int* __restrict__ ssrc,
    const float* __restrict__ BIAS,
    _Float16* __restrict__ X2H,
    const float* __restrict__ WL, const float* __restrict__ BL,
    float* __restrict__ OUT) {

    __shared__ float wslab[4][64 * 10];   // 10.2 KB; per-wave private slab

    const int tid  = threadIdx.x;
    const int lane = tid & 63;
    const int wid  = tid >> 6;
    const int node = __builtin_amdgcn_readfirstlane(blockIdx.x * 4 + wid);
    const int epar = lane >> 5;        // which edge of the pair (phase B)
    const int cg   = lane & 31;        // channel group: owns channels cg*8..cg*8+7
    const int hh   = cg >> 2;          // head of these channels
    const int c8   = cg * 8;
    float* wl = wslab[wid];

    const int p0  = rp[node];
    const int deg = rp[node + 1] - p0;   // >= 1 (self-loop)

    const float4 ad0 = *reinterpret_cast<const float4*>(&AD[node * NH]);
    const float4 ad1 = *reinterpret_cast<const float4*>(&AD[node * NH + 4]);

    float a0=0.f,a1=0.f,a2=0.f,a3=0.f,a4=0.f,a5=0.f,a6=0.f,a7=0.f;
    float den = 0.f;

    for (int base = 0; base < deg; base += 64) {
        const int ne = min(64, deg - base);

        // ---- phase A: lane e computes w[8] + src for edge base+e ----
        if (lane < ne) {
            int s = ssrc[p0 + base + lane];
            float4 as0 = *reinterpret_cast<const float4*>(&AS[s * NH]);
            float4 as1 = *reinterpret_cast<const float4*>(&AS[s * NH + 4]);
            float sv[8] = {as0.x + ad0.x, as0.y + ad0.y, as0.z + ad0.z, as0.w + ad0.w,
                           as1.x + ad1.x, as1.y + ad1.y, as1.z + ad1.z, as1.w + ad1.w};
            float* wp = &wl[lane * 10];
#pragma unroll
            for (int h = 0; h < 8; ++h) {
                float t = sv[h] > 0.f ? sv[h] : 0.2f * sv[h];
                wp[h] = __expf(t);
            }
            wp[8] = __int_as_float(s);
        }
        // wave-local LDS producer->consumer ordering (same wave, no barrier)
        asm volatile("s_waitcnt lgkmcnt(0)" ::: "memory");

        // ---- phase B: half-waves gather h rows; w + src from LDS ----
#pragma unroll 4
        for (int e0 = 0; e0 < ne; e0 += 2) {
            const int  e   = e0 + epar;
            const bool act = e < ne;
            const int  ee  = act ? e : 0;
            const int  sa  = __float_as_int(wl[ee * 10 + 8]);
            const float wr = wl[ee * 10 + hh];
            const float w  = act ? wr : 0.f;
            den += w;
            const f16x8 hv = *reinterpret_cast<const f16x8*>(&HFh[(size_t)sa * FH + c8]);
            a0 = fmaf((float)hv[0], w, a0);
            a1 = fmaf((float)hv[1], w, a1);
            a2 = fmaf((float)hv[2], w, a2);
            a3 = fmaf((float)hv[3], w, a3);
            a4 = fmaf((float)hv[4], w, a4);
            a5 = fmaf((float)hv[5], w, a5);
            a6 = fmaf((float)hv[6], w, a6);
            a7 = fmaf((float)hv[7], w, a7);
        }
    }

    // combine the two edge-parallel halves
    a0 += __shfl_xor(a0, 32); a1 += __shfl_xor(a1, 32);
    a2 += __shfl_xor(a2, 32); a3 += __shfl_xor(a3, 32);
    a4 += __shfl_xor(a4, 32); a5 += __shfl_xor(a5, 32);
    a6 += __shfl_xor(a6, 32); a7 += __shfl_xor(a7, 32);
    den += __shfl_xor(den, 32);

    const float inv = 1.f / (den + 1e-16f);
    const float4 b0 = *reinterpret_cast<const float4*>(&BIAS[c8]);
    const float4 b1 = *reinterpret_cast<const float4*>(&BIAS[c8 + 4]);
    float o[8];
    o[0] = fmaf(a0, inv, b0.x); o[1] = fmaf(a1, inv, b0.y);
    o[2] = fmaf(a2, inv, b0.z); o[3] = fmaf(a3, inv, b0.w);
    o[4] = fmaf(a4, inv, b1.x); o[5] = fmaf(a5, inv, b1.y);
    o[6] = fmaf(a6, inv, b1.z); o[7] = fmaf(a7, inv, b1.w);
#pragma unroll
    for (int j = 0; j < 8; ++j) o[j] = o[j] > 0.f ? o[j] : expm1f(o[j]);

    if (!FINAL) {
        // emit fp16 for the next GEMM (4 channels per half-wave)
        uint2 st;
        st.x = f2h2(o[epar * 4 + 0], o[epar * 4 + 1]);
        st.y = f2h2(o[epar * 4 + 2], o[epar * 4 + 3]);
        *reinterpret_cast<uint2*>(&X2H[(size_t)node * FH + c8 + epar * 4]) = st;
    } else {
        const float4 w0 = *reinterpret_cast<const float4*>(&WL[c8]);
        const float4 w1 = *reinterpret_cast<const float4*>(&WL[c8 + 4]);
        float pl = fmaf(o[0], w0.x, fmaf(o[1], w0.y, fmaf(o[2], w0.z, o[3] * w0.w)));
        pl = fmaf(o[4], w1.x, fmaf(o[5], w1.y, fmaf(o[6], w1.z, fmaf(o[7], w1.w, pl))));
#pragma unroll
        for (int off = 16; off >= 1; off >>= 1) pl += __shfl_xor(pl, off);
        if (lane == 0) OUT[node] = pl + BL[0];
    }
}

// ---------------- launch ----------------
extern "C" void kernel_launch(void* const* d_in, const int* in_sizes, int n_in,
                              void* d_out, int out_size, void* d_ws, size_t ws_size,
                              hipStream_t stream) {
    const float* x   = (const float*)d_in[0];
    const int*   ei  = (const int*)d_in[1];
    const float* W1  = (const float*)d_in[2];
    const float* a1s = (const float*)d_in[3];
    const float* a1d = (const float*)d_in[4];
    const float* b1  = (const float*)d_in[5];
    const float* W2  = (const float*)d_in[6];
    const float* a2s = (const float*)d_in[7];
    const float* a2d = (const float*)d_in[8];
    const float* b2  = (const float*)d_in[9];
    const float* Wl  = (const float*)d_in[10];
    const float* bl  = (const float*)d_in[11];
    float* out = (float*)d_out;

    char* w = (char*)d_ws;
    auto alloc = [&](size_t bytes) -> char* {
        char* p = w;
        w += (bytes + 255) & ~size_t(255);
        return p;
    };
    int*   counts = (int*)alloc((size_t)NNODES * 4);
    int*   rp     = (int*)alloc((size_t)(NNODES + 1) * 4);
    int*   cursor = (int*)alloc((size_t)NNODES * 4);
    unsigned long long* pub = (unsigned long long*)alloc((size_t)NSB * 8);
    int*   ssrc   = (int*)alloc((size_t)TE * 4);
    _Float16* hfh = (_Float16*)alloc((size_t)NNODES * FH * 2);
    _Float16* x2h = (_Float16*)alloc((size_t)NNODES * FH * 2);    // fp16 layer-2 A
    float* asb    = (float*)alloc((size_t)NNODES * NH * 4);
    float* adb    = (float*)alloc((size_t)NNODES * NH * 4);
    _Float16* w1t = (_Float16*)alloc((size_t)128 * 256 * 2);
    _Float16* w2t = (_Float16*)alloc((size_t)256 * 256 * 2);

    const int gblocks = (NNODES + 127) / 128;   // 235

    prep_kernel<<<384, 256, 0, stream>>>(counts, pub, W1, W2, w1t, w2t);
    // gemm1 + fused count role (extra CNTB blocks)
    gemm_mfma<128, true><<<gblocks + CNTB, 512, 0, stream>>>(
        x, w1t, a1s, a1d, hfh, asb, adb, gblocks, ei, counts);
    scan_lb<<<NSB, 256, 0, stream>>>(counts, rp, cursor, pub);
    fill_kernel<<<(TE + 511) / 512, 512, 0, stream>>>(ei, cursor, ssrc);
    aggregate<false><<<NNODES / 4, 256, 0, stream>>>(hfh, asb, adb, rp, ssrc, b1,
                                                     x2h, nullptr, nullptr, nullptr);
    gemm_mfma<256, false><<<gblocks, 512, 0, stream>>>(
        x2h, w2t, a2s, a2d, hfh, asb, adb, gblocks, nullptr, nullptr);
    aggregate<true><<<NNODES / 4, 256, 0, stream>>>(hfh, asb, adb, rp, ssrc, b2,
                                                    nullptr, Wl, bl, out);
}